// Round 4
// baseline (679.333 us; speedup 1.0000x reference)
//
#include <hip/hip_runtime.h>
#include <cstdint>
#include <cstddef>

// N=50000 nodes, E=500000 edges, EMB=64, PRED_IN=276.
// Padded-K bf16 MFMA layout (K=288 = 9*32):
//   pk   0.. 63 : q_emb     (k 0..63)
//   pk  64..127 : edge_attr (k 138..201)
//   pk 128..207 : h_e[src]  (k 64..137) + 6 pad
//   pk 208..287 : h_e[dst]  (k 202..275) + 6 pad
// h_e stored bf16 [N][80]: x(64) topic(2) f1(2) f2(2) r1(2) r2(2) pad(6).
//
// R4: k_gemm hoists all 18 A-frag loads per wave (latency evidence R3:
// MfmaUtil 5%/VALUBusy 5%/HBM 20% -> nothing busy); prep drops pos arrays
// and gives k_round 16 lanes/node (R3: 196 blocks was <1 block/CU).

typedef __bf16 bf16x8 __attribute__((ext_vector_type(8)));
typedef float f32x4 __attribute__((ext_vector_type(4)));

__device__ __forceinline__ unsigned int f2bf1(float f) {   // RNE fp32->bf16
    unsigned int u = __float_as_uint(f);
    return (u + 0x7fffu + ((u >> 16) & 1u)) >> 16;
}
__device__ __forceinline__ unsigned int pk2(float a, float b) {
    return f2bf1(a) | (f2bf1(b) << 16);
}
__device__ __forceinline__ bf16x8 cvt8(const float* __restrict__ p) {
    float4 v0 = *(const float4*)p;
    float4 v1 = *(const float4*)(p + 4);
    bf16x8 r;
    r[0] = (__bf16)v0.x; r[1] = (__bf16)v0.y; r[2] = (__bf16)v0.z; r[3] = (__bf16)v0.w;
    r[4] = (__bf16)v1.x; r[5] = (__bf16)v1.y; r[6] = (__bf16)v1.z; r[7] = (__bf16)v1.w;
    return r;
}

// ---------------------------------------------------------------------------
// Prep
// ---------------------------------------------------------------------------

__global__ void k_detect(const int* __restrict__ idx, int E, int* __restrict__ flag) {
    int e = blockIdx.x * blockDim.x + threadIdx.x;
    bool nz = (e < E) && (idx[2 * e + 1] != 0);
    unsigned long long m = __ballot(nz);
    if (m != 0ull && (threadIdx.x & 63) == 0) atomicOr(flag, 1);
}

// unpack indices + degree counts (2 int atomics/edge)
__global__ void k_convert(const int* __restrict__ idx, int E, const int* __restrict__ flag,
                          int* __restrict__ src_i, int* __restrict__ dst_i,
                          int* __restrict__ cnt_dst, int* __restrict__ cnt_src) {
    int e = blockIdx.x * blockDim.x + threadIdx.x;
    if (e >= E) return;
    int s, d;
    if (*flag) { s = idx[e];     d = idx[E + e]; }
    else       { s = idx[2 * e]; d = idx[2 * E + 2 * e]; }
    src_i[e] = s; dst_i[e] = d;
    atomicAdd(&cnt_dst[d], 1);
    atomicAdd(&cnt_src[s], 1);
}

// exclusive scan; block 0: cnt_dst -> off_f+cur_f, block 1: cnt_src -> off_r+cur_r
__global__ void k_scan(const int* __restrict__ cnt_dst, const int* __restrict__ cnt_src,
                       int* __restrict__ off_f, int* __restrict__ off_r,
                       int* __restrict__ cur_f, int* __restrict__ cur_r, int N) {
    const int* cnt = (blockIdx.x == 0) ? cnt_dst : cnt_src;
    int* off       = (blockIdx.x == 0) ? off_f   : off_r;
    int* cur       = (blockIdx.x == 0) ? cur_f   : cur_r;
    const int t = threadIdx.x;                 // 1024 threads
    const int C = (N + 1023) / 1024;
    int lo = t * C, hi = lo + C; if (hi > N) hi = N; if (lo > N) lo = N;
    int sum = 0;
    for (int i = lo; i < hi; ++i) sum += cnt[i];
    __shared__ int wsum[16];
    int lane = t & 63, wv = t >> 6;
    int v = sum;
    for (int ofs = 1; ofs < 64; ofs <<= 1) {
        int u = __shfl_up(v, ofs);
        if (lane >= ofs) v += u;
    }
    if (lane == 63) wsum[wv] = v;
    __syncthreads();
    if (wv == 0) {
        int x = (lane < 16) ? wsum[lane] : 0;
        for (int ofs = 1; ofs < 16; ofs <<= 1) {
            int u = __shfl_up(x, ofs);
            if (lane >= ofs) x += u;
        }
        if (lane < 16) wsum[lane] = x;
    }
    __syncthreads();
    int base = (wv > 0 ? wsum[wv - 1] : 0) + (v - sum);
    for (int i = lo; i < hi; ++i) { off[i] = base; cur[i] = base; base += cnt[i]; }
}

// CSR fill via atomic slot grab (order nondeterminism only perturbs fp rounding)
__global__ void k_fill(const int* __restrict__ src_i, const int* __restrict__ dst_i,
                       int* __restrict__ cur_f, int* __restrict__ cur_r,
                       int* __restrict__ csr_f, int* __restrict__ csr_r, int E) {
    int e = blockIdx.x * blockDim.x + threadIdx.x;
    if (e >= E) return;
    int s = src_i[e], d = dst_i[e];
    csr_f[atomicAdd(&cur_f[d], 1)] = s;
    csr_r[atomicAdd(&cur_r[s], 1)] = d;
}

// atomic-free segment means, 16 lanes per node (fwd+rev in one pass)
__global__ void k_round(const int* __restrict__ off_f, const int* __restrict__ csr_f,
                        const int* __restrict__ off_r, const int* __restrict__ csr_r,
                        const float* __restrict__ hf_in, const float* __restrict__ hr_in,
                        float* __restrict__ f_out, float* __restrict__ r_out,
                        int N, int E) {
    int n   = blockIdx.x * 16 + (threadIdx.x >> 4);
    int sub = threadIdx.x & 15;
    if (n >= N) return;
    const float2* hf = (const float2*)hf_in;
    const float2* hr = (const float2*)hr_in;
    {
        int b = off_f[n], en = (n + 1 < N) ? off_f[n + 1] : E;
        float sx = 0.f, sy = 0.f;
        for (int j = b + sub; j < en; j += 16) { float2 t = hf[csr_f[j]]; sx += t.x; sy += t.y; }
        sx += __shfl_xor(sx, 1); sy += __shfl_xor(sy, 1);
        sx += __shfl_xor(sx, 2); sy += __shfl_xor(sy, 2);
        sx += __shfl_xor(sx, 4); sy += __shfl_xor(sy, 4);
        sx += __shfl_xor(sx, 8); sy += __shfl_xor(sy, 8);
        if (sub == 0) {
            float inv = 1.0f / (float)max(en - b, 1);
            ((float2*)f_out)[n] = make_float2(sx * inv, sy * inv);
        }
    }
    {
        int b = off_r[n], en = (n + 1 < N) ? off_r[n + 1] : E;
        float sx = 0.f, sy = 0.f;
        for (int j = b + sub; j < en; j += 16) { float2 t = hr[csr_r[j]]; sx += t.x; sy += t.y; }
        sx += __shfl_xor(sx, 1); sy += __shfl_xor(sy, 1);
        sx += __shfl_xor(sx, 2); sy += __shfl_xor(sy, 2);
        sx += __shfl_xor(sx, 4); sy += __shfl_xor(sy, 4);
        sx += __shfl_xor(sx, 8); sy += __shfl_xor(sy, 8);
        if (sub == 0) {
            float inv = 1.0f / (float)max(en - b, 1);
            ((float2*)r_out)[n] = make_float2(sx * inv, sy * inv);
        }
    }
}

// build bf16 h_e row (all feature buffers pre-normalized)
__global__ void k_build(const float* __restrict__ x, const float* __restrict__ topic,
                        const float* __restrict__ nte,
                        const float* __restrict__ f1, const float* __restrict__ f2,
                        const float* __restrict__ r1, const float* __restrict__ r2,
                        unsigned short* __restrict__ he, int N) {
    int n = blockIdx.x * blockDim.x + threadIdx.x;
    if (n >= N) return;
    const float4* xr = (const float4*)(x + (size_t)n * 64);
    float4 v[16];
    bool allz = true;
#pragma unroll
    for (int i = 0; i < 16; ++i) {
        v[i] = xr[i];
        allz = allz && (v[i].x == 0.f && v[i].y == 0.f && v[i].z == 0.f && v[i].w == 0.f);
    }
    const float4* nr = (const float4*)nte;
    unsigned int row[40];
#pragma unroll
    for (int i = 0; i < 16; ++i) {
        float4 s = allz ? nr[i] : v[i];
        row[2 * i]     = pk2(s.x, s.y);
        row[2 * i + 1] = pk2(s.z, s.w);
    }
    row[32] = pk2(topic[2 * n], topic[2 * n + 1]);
    row[33] = pk2(f1[2 * n], f1[2 * n + 1]);
    row[34] = pk2(f2[2 * n], f2[2 * n + 1]);
    row[35] = pk2(r1[2 * n], r1[2 * n + 1]);
    row[36] = pk2(r2[2 * n], r2[2 * n + 1]);
    row[37] = 0u; row[38] = 0u; row[39] = 0u;
    uint4* dst = (uint4*)(he + (size_t)n * 80);
#pragma unroll
    for (int i = 0; i < 10; ++i) dst[i] = ((const uint4*)row)[i];
}

// padded bf16 W1^T [64 cols][288 pk]
__global__ void k_w1t(const float* __restrict__ W1, unsigned short* __restrict__ W1T) {
    int i = blockIdx.x * blockDim.x + threadIdx.x;
    if (i >= 64 * 288) return;
    int col = i / 288, pk = i - col * 288;
    int k = 0; bool valid = true;
    if (pk < 64)       { k = pk; }
    else if (pk < 128) { k = 138 + (pk - 64); }
    else if (pk < 208) { int j = pk - 128; k = 64 + j;  valid = j < 74; }
    else               { int j = pk - 208; k = 202 + j; valid = j < 74; }
    float v = valid ? W1[k * 64 + col] : 0.f;
    W1T[col * 288 + pk] = (unsigned short)f2bf1(v);
}

// ---------------------------------------------------------------------------
// MFMA edge-MLP: 128 edges/block, 4 waves, 32 edges/wave (2 M-tiles).
// All 18 A-frag loads per wave hoisted to wave start (HBM streams + L3 he
// gathers all in flight at once); B-frags from L2-resident W1T, one step ahead.
// ---------------------------------------------------------------------------

__launch_bounds__(256, 3)
__global__ void k_gemm(const float* __restrict__ q_emb,
                       const float* __restrict__ edge_attr,
                       const unsigned short* __restrict__ he,
                       const unsigned short* __restrict__ W1T,
                       const int* __restrict__ src_i, const int* __restrict__ dst_i,
                       const float* __restrict__ b1, const float* __restrict__ W2,
                       const float* __restrict__ b2, float* __restrict__ out, int E)
{
    const int tid = threadIdx.x;
    const int w = tid >> 6, l = tid & 63, c = l & 15, q = l >> 4;
    const int ebase = blockIdx.x * 128 + w * 32;

    bf16x8 A[2][9];
#pragma unroll
    for (int t = 0; t < 2; ++t) {
        int ee = ebase + t * 16 + c; ee = ee < E ? ee : E - 1;
        int s = src_i[ee], d = dst_i[ee];
        const float* gq = q_emb     + (size_t)ee * 64 + q * 8;
        const float* ga = edge_attr + (size_t)ee * 64 + q * 8;
        const unsigned short* phs = he + (size_t)s * 80 + q * 8;
        const unsigned short* phd = he + (size_t)d * 80 + q * 8;
        A[t][0] = cvt8(gq);
        A[t][1] = cvt8(gq + 32);
        A[t][2] = cvt8(ga);
        A[t][3] = cvt8(ga + 32);
        A[t][4] = *(const bf16x8*)(phs);
        A[t][5] = *(const bf16x8*)(phs + 32);
        A[t][6] = *(const bf16x8*)((q < 2) ? (phs + 64) : (phd - 16));
        A[t][7] = *(const bf16x8*)(phd + 16);
        A[t][8] = *(const bf16x8*)(phd + 48);
    }

    float b1v[4], w2v[4];
#pragma unroll
    for (int ct = 0; ct < 4; ++ct) { b1v[ct] = b1[ct * 16 + c]; w2v[ct] = W2[ct * 16 + c]; }
    const float bb = b2[0];

    f32x4 acc[2][4] = {};
    const unsigned short* wrow = W1T + (size_t)c * 288 + q * 8;

    bf16x8 Bn[4];
#pragma unroll
    for (int ct = 0; ct < 4; ++ct) Bn[ct] = *(const bf16x8*)(wrow + ct * (16 * 288));

#pragma unroll
    for (int ks = 0; ks < 9; ++ks) {
        bf16x8 Bc[4];
#pragma unroll
        for (int ct = 0; ct < 4; ++ct) Bc[ct] = Bn[ct];
        if (ks < 8) {
#pragma unroll
            for (int ct = 0; ct < 4; ++ct)
                Bn[ct] = *(const bf16x8*)(wrow + ct * (16 * 288) + (ks + 1) * 32);
        }
#pragma unroll
        for (int t = 0; t < 2; ++t) {
#pragma unroll
            for (int ct = 0; ct < 4; ++ct)
                acc[t][ct] = __builtin_amdgcn_mfma_f32_16x16x32_bf16(A[t][ks], Bc[ct],
                                                                     acc[t][ct], 0, 0, 0);
        }
    }

#pragma unroll
    for (int t = 0; t < 2; ++t) {
        float pr[4];
#pragma unroll
        for (int r = 0; r < 4; ++r) {
            float h0 = fmaxf(acc[t][0][r] + b1v[0], 0.f);
            float h1 = fmaxf(acc[t][1][r] + b1v[1], 0.f);
            float h2 = fmaxf(acc[t][2][r] + b1v[2], 0.f);
            float h3 = fmaxf(acc[t][3][r] + b1v[3], 0.f);
            float p = fmaf(h0, w2v[0], fmaf(h1, w2v[1], fmaf(h2, w2v[2], h3 * w2v[3])));
            p += __shfl_xor(p, 1);
            p += __shfl_xor(p, 2);
            p += __shfl_xor(p, 4);
            p += __shfl_xor(p, 8);
            pr[r] = p;
        }
        if (c == 0) {
            int eo = ebase + t * 16 + q * 4;     // E % 16 == 0: tiles fully valid or fully out
            if (eo < E) {
                float4 o = make_float4(pr[0] + bb, pr[1] + bb, pr[2] + bb, pr[3] + bb);
                *(float4*)&out[eo] = o;
            }
        }
    }
}

// ---------------------------------------------------------------------------
// Launch
// ---------------------------------------------------------------------------

extern "C" void kernel_launch(void* const* d_in, const int* in_sizes, int n_in,
                              void* d_out, int out_size, void* d_ws, size_t ws_size,
                              hipStream_t stream)
{
    const float* x         = (const float*)d_in[0];
    const int*   eidx      = (const int*)  d_in[1];
    const float* edge_attr = (const float*)d_in[2];
    const float* topic     = (const float*)d_in[3];
    const float* q_emb     = (const float*)d_in[4];
    const float* nte       = (const float*)d_in[5];
    const float* W1        = (const float*)d_in[6];
    const float* b1        = (const float*)d_in[7];
    const float* W2        = (const float*)d_in[8];
    const float* b2        = (const float*)d_in[9];
    float* out = (float*)d_out;

    const int E = out_size;             // 500000
    const int N = in_sizes[0] / 64;     // 50000

    // Workspace:
    // [flag 16][src_i 4E][dst_i 4E][cnt_dst 4N][cnt_src 4N][off_f 4N][off_r 4N]
    // [cur_f 4N][cur_r 4N][f1..r2 32N][heblk max(160N, 8E)][W1T 36864]
    char* ws = (char*)d_ws;
    int* flag    = (int*)ws;
    int* src_i   = (int*)(ws + 16);
    int* dst_i   = src_i + E;
    int* cnt_dst = dst_i + E;
    int* cnt_src = cnt_dst + N;
    int* off_f   = cnt_src + N;
    int* off_r   = off_f + N;
    int* cur_f   = off_r + N;
    int* cur_r   = cur_f + N;
    float* f1 = (float*)(cur_r + N);
    float* f2 = f1 + 2 * (size_t)N;
    float* r1 = f2 + 2 * (size_t)N;
    float* r2 = r1 + 2 * (size_t)N;
    char* heblk = (char*)(r2 + 2 * (size_t)N);
    int* csr_f = (int*)heblk;                       // dead before he is written
    int* csr_r = csr_f + E;
    unsigned short* he = (unsigned short*)heblk;
    size_t he_bytes = (size_t)N * 160;
    size_t csr_bytes = (size_t)E * 8;
    size_t heblk_bytes = he_bytes > csr_bytes ? he_bytes : csr_bytes;
    unsigned short* W1T = (unsigned short*)(heblk + heblk_bytes);

    size_t needed = 16 + (size_t)8 * E + (size_t)24 * N + (size_t)32 * N
                  + heblk_bytes + 64 * 288 * 2;
    if (ws_size < needed) return;

    hipMemsetAsync(flag, 0, 16, stream);
    hipMemsetAsync(cnt_dst, 0, (size_t)8 * N, stream);   // both cnt arrays

    const int gE = (E + 255) / 256;
    const int gN = (N + 255) / 256;
    const int gRN = (N + 15) / 16;          // k_round: 16 lanes/node

    k_detect <<<gE, 256, 0, stream>>>(eidx, E, flag);
    k_convert<<<gE, 256, 0, stream>>>(eidx, E, flag, src_i, dst_i, cnt_dst, cnt_src);
    k_scan   <<<2, 1024, 0, stream>>>(cnt_dst, cnt_src, off_f, off_r, cur_f, cur_r, N);
    k_fill   <<<gE, 256, 0, stream>>>(src_i, dst_i, cur_f, cur_r, csr_f, csr_r, E);
    k_round  <<<gRN, 256, 0, stream>>>(off_f, csr_f, off_r, csr_r, topic, topic, f1, r1, N, E);
    k_round  <<<gRN, 256, 0, stream>>>(off_f, csr_f, off_r, csr_r, f1, r1, f2, r2, N, E);
    k_build  <<<gN, 256, 0, stream>>>(x, topic, nte, f1, f2, r1, r2, he, N);
    k_w1t    <<<(64 * 288 + 255) / 256, 256, 0, stream>>>(W1, W1T);

    k_gemm<<<(E + 127) / 128, 256, 0, stream>>>(q_emb, edge_attr, he, W1T,
                                                src_i, dst_i, b1, W2, b2, out, E);
}